// Round 6
// baseline (1688.464 us; speedup 1.0000x reference)
//
#include <hip/hip_runtime.h>
#include <math.h>

// Problem constants (from reference): N_EDGES=500000, N_NODES=200000, D=256, R=256.
#define D 256
#define R 256
#define DIMC 32        // dims per y-block in node_accum (8 chunks)
#define NODE_CHUNKS 64 // x-blocks in node_accum -> 512 blocks, 2/CU

__device__ __forceinline__ float sigmoidf(float x) {
    return 1.0f / (1.0f + expf(-x));
}

// ---- zero helpers (harness poisons ws with 0xAA every call) ----
__global__ void zero_f(float* p, int n) {
    int i = blockIdx.x * blockDim.x + threadIdx.x;
    if (i < n) p[i] = 0.0f;
}
__global__ void zero_i(int* p, int n) {
    int i = blockIdx.x * blockDim.x + threadIdx.x;
    if (i < n) p[i] = 0;
}

// ---- per-relation edge counts (float, integer-exact) ----
__global__ __launch_bounds__(256) void hist_rel(const int* __restrict__ rel,
                                                int E, float* __restrict__ counts) {
    __shared__ int h[R];
    h[threadIdx.x] = 0;
    __syncthreads();
    for (int e = blockIdx.x * blockDim.x + threadIdx.x; e < E;
         e += gridDim.x * blockDim.x)
        atomicAdd(&h[rel[e]], 1);
    __syncthreads();
    atomicAdd(&counts[threadIdx.x], (float)h[threadIdx.x]);
}

// ---- counting sort phase 1: per-node incidence counts ----
__global__ __launch_bounds__(256) void hist_nodes(const int* __restrict__ src,
                                                  const int* __restrict__ dst,
                                                  int E, int* __restrict__ cnt) {
    int i = blockIdx.x * blockDim.x + threadIdx.x;
    if (i < 2 * E) {
        int n = (i < E) ? src[i] : dst[i - E];
        atomicAdd(&cnt[n], 1);
    }
}

// ---- counting sort phase 2: exclusive prefix scan over N node counts ----
__global__ __launch_bounds__(1024) void scan1(const int* __restrict__ cnt, int N,
                                              int* __restrict__ offs,
                                              int* __restrict__ bsum) {
    __shared__ int s[1024];
    int t = threadIdx.x, i = blockIdx.x * 1024 + t;
    int x = (i < N) ? cnt[i] : 0;
    s[t] = x;
    __syncthreads();
    for (int o = 1; o < 1024; o <<= 1) {
        int v = (t >= o) ? s[t - o] : 0;
        __syncthreads();
        s[t] += v;
        __syncthreads();
    }
    if (i < N) offs[i] = s[t] - x;  // exclusive within block
    if (t == 1023) bsum[blockIdx.x] = s[t];
}
__global__ __launch_bounds__(1024) void scan2(const int* __restrict__ bsum, int NB,
                                              int* __restrict__ bexcl) {
    __shared__ int s[1024];
    int t = threadIdx.x;
    int x = (t < NB) ? bsum[t] : 0;
    s[t] = x;
    __syncthreads();
    for (int o = 1; o < 1024; o <<= 1) {
        int v = (t >= o) ? s[t - o] : 0;
        __syncthreads();
        s[t] += v;
        __syncthreads();
    }
    if (t < NB) bexcl[t] = s[t] - x;
}
__global__ __launch_bounds__(1024) void scan3(int* __restrict__ offs, int N,
                                              const int* __restrict__ bexcl,
                                              int total) {
    int t = threadIdx.x, i = blockIdx.x * 1024 + t;
    if (i < N) offs[i] += bexcl[blockIdx.x];
    if (i == 0) offs[N] = total;  // sentinel: counts via offs[n+1]-offs[n]
}

// ---- counting sort phase 3: scatter (rel|side) payloads into node buckets ----
__global__ __launch_bounds__(256) void build_pay(const int* __restrict__ src,
                                                 const int* __restrict__ dst,
                                                 const int* __restrict__ rel, int E,
                                                 const int* __restrict__ offs,
                                                 int* __restrict__ cursor,
                                                 unsigned short* __restrict__ pay) {
    int i = blockIdx.x * blockDim.x + threadIdx.x;
    if (i >= 2 * E) return;
    int side = (i >= E) ? 1 : 0;
    int e = side ? i - E : i;
    int n = side ? dst[e] : src[e];
    int r = rel[e];
    int pos = offs[n] + atomicAdd(&cursor[n], 1);
    pay[pos] = (unsigned short)(r | (side << 8));
}

// ---- node-centric accumulate: stream the table once, coalesced ----
// Block = (node range, 32-dim chunk). acc[side][rel][32] = 64 KB -> 2 blk/CU.
// Wave handles 2 nodes per step (half-wave each); per incident payload entry,
// ds_add the 32-dim row slice (stride-1 per half-wave -> 2-way aliasing, free).
__global__ __launch_bounds__(256) void node_accum(const float* __restrict__ emb,
                                                  const int* __restrict__ offs,
                                                  const unsigned short* __restrict__ pay,
                                                  float* __restrict__ src_sum,
                                                  float* __restrict__ dst_sum,
                                                  int N, int npb) {
    __shared__ float acc[2 * R * DIMC];  // 64 KB
    const int tid = threadIdx.x;
    for (int i = tid; i < 2 * R * DIMC; i += 256) acc[i] = 0.0f;
    __syncthreads();

    const int dimbase = blockIdx.y * DIMC;
    const int wave = tid >> 6, lane = tid & 63;
    const int half = lane >> 5, m = lane & 31;
    const int n0 = blockIdx.x * npb;
    const int n1 = (n0 + npb < N) ? (n0 + npb) : N;

    int n = n0 + wave * 2;
    float v = 0.0f;
    if (n + half < n1) v = emb[(size_t)(n + half) * D + dimbase + m];
    for (; n < n1; n += 8) {
        int nA = n + half;
        // prefetch next pair's row while processing payloads
        float vnext = 0.0f;
        int nn = n + 8 + half;
        if (nn < n1) vnext = emb[(size_t)nn * D + dimbase + m];
        if (nA < n1) {
            int oA = offs[nA];
            int cA = offs[nA + 1] - oA;
            for (int k = 0; k < cA; k++) {
                int p = pay[oA + k];
                int r = p & 255, side = p >> 8;
                atomicAdd(&acc[(side << 13) + (r << 5) + m], v);
            }
        }
        v = vnext;
    }
    __syncthreads();
    for (int i = tid; i < 2 * R * DIMC; i += 256) {
        int side = i >> 13, r = (i >> 5) & 255, mm = i & 31;
        float* g = side ? dst_sum : src_sum;
        atomicAdd(&g[r * D + dimbase + mm], acc[i]);
    }
}

// ---- means + GRU cell for src and dst, one block per relation ----
__global__ __launch_bounds__(256) void gru_kernel(
    const float* __restrict__ src_sum, const float* __restrict__ dst_sum,
    const float* __restrict__ counts, const float* __restrict__ dyn,
    const float* __restrict__ W_ih, const float* __restrict__ W_hh,
    const float* __restrict__ b_ih, const float* __restrict__ b_hh,
    float* __restrict__ out) {
    __shared__ float xs[D], xd[D], hs[D], hd[D];
    const int r = blockIdx.x, t = threadIdx.x;
    float inv = 1.0f / fmaxf(counts[r], 1.0f);
    xs[t] = src_sum[r * D + t] * inv;
    xd[t] = dst_sum[r * D + t] * inv;
    float h_s = dyn[(r * D + t) * 2 + 0];
    float h_d = dyn[(r * D + t) * 2 + 1];
    hs[t] = h_s;
    hd[t] = h_d;
    __syncthreads();

    float gis[3], gid[3], ghs[3], ghd[3];
#pragma unroll
    for (int g = 0; g < 3; g++) {
        int row = g * D + t;
        const float4* wi = (const float4*)(W_ih + (size_t)row * D);
        const float4* wh = (const float4*)(W_hh + (size_t)row * D);
        float ais = 0.f, aid = 0.f, ahs = 0.f, ahd = 0.f;
        for (int k = 0; k < D / 4; k++) {
            float4 a = wi[k];
            float4 b = wh[k];
            int k4 = k * 4;
            ais += a.x * xs[k4] + a.y * xs[k4 + 1] + a.z * xs[k4 + 2] + a.w * xs[k4 + 3];
            aid += a.x * xd[k4] + a.y * xd[k4 + 1] + a.z * xd[k4 + 2] + a.w * xd[k4 + 3];
            ahs += b.x * hs[k4] + b.y * hs[k4 + 1] + b.z * hs[k4 + 2] + b.w * hs[k4 + 3];
            ahd += b.x * hd[k4] + b.y * hd[k4 + 1] + b.z * hd[k4 + 2] + b.w * hd[k4 + 3];
        }
        float bi = b_ih[row];
        float bh = b_hh[row];
        gis[g] = ais + bi; gid[g] = aid + bi;
        ghs[g] = ahs + bh; ghd[g] = ahd + bh;
    }
    float rs = sigmoidf(gis[0] + ghs[0]);
    float zs = sigmoidf(gis[1] + ghs[1]);
    float ns = tanhf(gis[2] + rs * ghs[2]);
    float new_s = (1.0f - zs) * ns + zs * h_s;

    float rd = sigmoidf(gid[0] + ghd[0]);
    float zd = sigmoidf(gid[1] + ghd[1]);
    float nd = tanhf(gid[2] + rd * ghd[2]);
    float new_d = (1.0f - zd) * nd + zd * h_d;

    out[(r * D + t) * 2 + 0] = new_s;
    out[(r * D + t) * 2 + 1] = new_d;
}

extern "C" void kernel_launch(void* const* d_in, const int* in_sizes, int n_in,
                              void* d_out, int out_size, void* d_ws, size_t ws_size,
                              hipStream_t stream) {
    const int* src_nid = (const int*)d_in[0];
    const int* dst_nid = (const int*)d_in[1];
    const int* rel     = (const int*)d_in[2];
    const float* emb   = (const float*)d_in[3];
    const float* dyn   = (const float*)d_in[4];
    const float* W_ih  = (const float*)d_in[5];
    const float* W_hh  = (const float*)d_in[6];
    const float* b_ih  = (const float*)d_in[7];
    const float* b_hh  = (const float*)d_in[8];
    float* out = (float*)d_out;
    const int E = in_sizes[0];
    const int N = in_sizes[3] / D;  // 200000

    // ---- workspace layout ----
    float* ws      = (float*)d_ws;
    float* src_sum = ws;                 // R*D
    float* dst_sum = ws + R * D;         // R*D
    float* counts  = ws + 2 * R * D;     // R
    const int nzf  = 2 * R * D + R;
    int* cnt    = (int*)(ws + nzf);      // N
    int* cursor = cnt + N;               // N
    int* offs   = cursor + N;            // N+1
    int* bsum   = offs + N + 1;          // 1024
    int* bexcl  = bsum + 1024;           // 1024
    unsigned short* pay = (unsigned short*)(bexcl + 1024);  // 2E

    const int NB  = (N + 1023) / 1024;              // scan blocks (196)
    const int npb = (N + NODE_CHUNKS - 1) / NODE_CHUNKS;

    zero_f<<<(nzf + 255) / 256, 256, 0, stream>>>(ws, nzf);
    zero_i<<<(2 * N + 255) / 256, 256, 0, stream>>>(cnt, 2 * N);  // cnt+cursor
    hist_rel<<<256, 256, 0, stream>>>(rel, E, counts);
    hist_nodes<<<(2 * E + 255) / 256, 256, 0, stream>>>(src_nid, dst_nid, E, cnt);
    scan1<<<NB, 1024, 0, stream>>>(cnt, N, offs, bsum);
    scan2<<<1, 1024, 0, stream>>>(bsum, NB, bexcl);
    scan3<<<NB, 1024, 0, stream>>>(offs, N, bexcl, 2 * E);
    build_pay<<<(2 * E + 255) / 256, 256, 0, stream>>>(src_nid, dst_nid, rel, E,
                                                       offs, cursor, pay);
    node_accum<<<dim3(NODE_CHUNKS, D / DIMC), 256, 0, stream>>>(
        emb, offs, pay, src_sum, dst_sum, N, npb);
    gru_kernel<<<R, 256, 0, stream>>>(src_sum, dst_sum, counts, dyn, W_ih, W_hh,
                                      b_ih, b_hh, out);
}